// Round 3
// baseline (919.894 us; speedup 1.0000x reference)
//
#include <hip/hip_runtime.h>
#include <hip/hip_fp16.h>
#include <stdint.h>

#define TOKENS 4096
#define IN_F   4096
#define OUT_F  11008

#define BM  128
#define BN  128
#define BK  32
#define NKT (IN_F / BK)   // 128 K-tiles

typedef _Float16 half8 __attribute__((ext_vector_type(8)));
typedef float    f32x4 __attribute__((ext_vector_type(4)));

typedef const __attribute__((address_space(1))) uint32_t* gptr_t;
typedef __attribute__((address_space(3))) uint32_t*       lptr_t;

__device__ inline void gl2lds16(const void* g, void* l) {
  __builtin_amdgcn_global_load_lds((gptr_t)g, (lptr_t)l, 16, 0, 0);
}

// ---------------- pre-pass 1: x fp32 -> f16 ----------------
__global__ __launch_bounds__(256)
void convert_x_kernel(const float* __restrict__ x, __half* __restrict__ xh) {
  const int gi = (blockIdx.x * 256 + threadIdx.x) * 8;
  float4 a = *(const float4*)(x + gi);
  float4 b = *(const float4*)(x + gi + 4);
  union { __half2 h2[4]; uint4 u; } o;
  o.h2[0] = __floats2half2_rn(a.x, a.y);
  o.h2[1] = __floats2half2_rn(a.z, a.w);
  o.h2[2] = __floats2half2_rn(b.x, b.y);
  o.h2[3] = __floats2half2_rn(b.z, b.w);
  *(uint4*)(xh + gi) = o.u;
}

// ---------------- pre-pass 2: W int4 (one byte per int32) -> f16 ----------------
__device__ inline __half2 dq_byte(int v, float s, float nzs) {
  float lo = fmaf((float)(v & 15), s, nzs);
  float hi = fmaf((float)((v >> 4) & 15), s, nzs);
  return __floats2half2_rn(lo, hi);   // (k_even, k_odd), fp32 math, single rounding
}

__global__ __launch_bounds__(256)
void dequant_w_kernel(const int* __restrict__ wq, const float* __restrict__ scale,
                      const float* __restrict__ zero, __half* __restrict__ wh) {
  const int gi  = (blockIdx.x * 256 + threadIdx.x) * 8;  // int32 (packed-byte) index
  const int row = gi >> 11;                              // 2048 packed bytes per row
  const float s   = scale[row];
  const float nzs = -zero[row] * s;
  int4 p0 = *(const int4*)(wq + gi);
  int4 p1 = *(const int4*)(wq + gi + 4);
  union { __half2 h2[4]; uint4 u; } o0, o1;
  o0.h2[0] = dq_byte(p0.x, s, nzs);  o0.h2[1] = dq_byte(p0.y, s, nzs);
  o0.h2[2] = dq_byte(p0.z, s, nzs);  o0.h2[3] = dq_byte(p0.w, s, nzs);
  o1.h2[0] = dq_byte(p1.x, s, nzs);  o1.h2[1] = dq_byte(p1.y, s, nzs);
  o1.h2[2] = dq_byte(p1.z, s, nzs);  o1.h2[3] = dq_byte(p1.w, s, nzs);
  *(uint4*)(wh + (size_t)gi * 2)     = o0.u;
  *(uint4*)(wh + (size_t)gi * 2 + 8) = o1.u;
}

// ---------------- main: f16 GEMM, m97 structure (global_load_lds staging) ----------------
__global__ __launch_bounds__(256, 2)
void gemm_f16_kernel(const __half* __restrict__ Ah, const __half* __restrict__ Bh,
                     float* __restrict__ out) {
  __shared__ __half As[BM * BK];   // 8 KB, unpadded: layout = staging order
  __shared__ __half Bs[BN * BK];   // 8 KB

  const int tid  = threadIdx.x;
  const int n0   = blockIdx.x * BN;
  const int m0   = blockIdx.y * BM;
  const int lane = tid & 63;
  const int wave = tid >> 6;
  const int wm   = (wave >> 1) * 64;
  const int wn   = (wave & 1) * 64;

  // staging chunks: c in [0,512), row = c>>2, 16B-col = c&3; thread does c=tid and c=tid+256
  const int srow = tid >> 2;
  const int scol = (tid & 3) * 8;    // halves
  const char* ga0 = (const char*)(Ah + (size_t)(m0 + srow)      * IN_F + scol);
  const char* ga1 = (const char*)(Ah + (size_t)(m0 + srow + 64) * IN_F + scol);
  const char* gb0 = (const char*)(Bh + (size_t)(n0 + srow)      * IN_F + scol);
  const char* gb1 = (const char*)(Bh + (size_t)(n0 + srow + 64) * IN_F + scol);
  char* la0 = (char*)As + tid * 16;
  char* la1 = (char*)As + tid * 16 + 4096;
  char* lb0 = (char*)Bs + tid * 16;
  char* lb1 = (char*)Bs + tid * 16 + 4096;

  f32x4 acc[4][4];
#pragma unroll
  for (int i = 0; i < 4; ++i)
#pragma unroll
    for (int j = 0; j < 4; ++j)
      acc[i][j] = (f32x4){0.f, 0.f, 0.f, 0.f};

  const int fm = lane & 15;
  const int q4 = lane >> 4;

  for (int kt = 0; kt < NKT; ++kt) {
    gl2lds16(ga0, la0);
    gl2lds16(ga1, la1);
    gl2lds16(gb0, lb0);
    gl2lds16(gb1, lb1);
    ga0 += BK * 2; ga1 += BK * 2; gb0 += BK * 2; gb1 += BK * 2;
    __syncthreads();   // compiler emits vmcnt(0) drain before barrier

    half8 af[4], bf[4];
#pragma unroll
    for (int i = 0; i < 4; ++i)
      af[i] = *reinterpret_cast<const half8*>(&As[(wm + i * 16 + fm) * BK + q4 * 8]);
#pragma unroll
    for (int j = 0; j < 4; ++j)
      bf[j] = *reinterpret_cast<const half8*>(&Bs[(wn + j * 16 + fm) * BK + q4 * 8]);
#pragma unroll
    for (int i = 0; i < 4; ++i)
#pragma unroll
      for (int j = 0; j < 4; ++j)
        acc[i][j] = __builtin_amdgcn_mfma_f32_16x16x32_f16(af[i], bf[j], acc[i][j], 0, 0, 0);
    __syncthreads();
  }

  // epilogue: C/D layout col=lane&15 (n), row=(lane>>4)*4+reg (m)
  const int col = lane & 15;
  const int r0q = (lane >> 4) * 4;
#pragma unroll
  for (int i = 0; i < 4; ++i)
#pragma unroll
    for (int j = 0; j < 4; ++j)
#pragma unroll
      for (int r = 0; r < 4; ++r) {
        const int m = m0 + wm + i * 16 + r0q + r;
        const int n = n0 + wn + j * 16 + col;
        out[(size_t)m * OUT_F + n] = acc[i][j][r];
      }
}

// ---------------- fallback: round-2 fused kernel (used only if ws too small) ----------------
#define LDT 40
union H4 { __half2 h2[2]; uint2 u2; };
union H8 { __half2 h2[4]; uint4 u4; };

__device__ inline __half2 dequant_byte(int v, __half2 s2, __half2 b2) {
  float lo = (float)(v & 15);
  float hi = (float)((v >> 4) & 15);
  return __hfma2(__floats2half2_rn(lo, hi), s2, b2);
}

__global__ __launch_bounds__(256, 2)
void int4_gemm_fused_kernel(const float* __restrict__ x, const int* __restrict__ wq,
                            const float* __restrict__ scale, const float* __restrict__ zero,
                            float* __restrict__ out) {
  __shared__ __half As[BM * LDT];
  __shared__ __half Bs[BN * LDT];
  const int tid = threadIdx.x, n0 = blockIdx.x * BN, m0 = blockIdx.y * BM;
  const int lane = tid & 63, wave = tid >> 6;
  const int wm = (wave >> 1) * 64, wn = (wave & 1) * 64;
  const int rowb = tid >> 1, bhalf = tid & 1;
  const float s = scale[n0 + rowb], z = zero[n0 + rowb];
  const __half2 s2 = __floats2half2_rn(s, s);
  const float nb = -z * s;
  const __half2 b2 = __floats2half2_rn(nb, nb);
  const int* wp = wq + (size_t)(n0 + rowb) * (IN_F / 2) + bhalf * 8;
  const float* xp[4]; int arow[4], ac4[4];
#pragma unroll
  for (int i = 0; i < 4; ++i) {
    int idx = tid + i * 256; arow[i] = idx >> 3; ac4[i] = idx & 7;
    xp[i] = x + (size_t)(m0 + arow[i]) * IN_F + ac4[i] * 4;
  }
  f32x4 acc[4][4];
#pragma unroll
  for (int i = 0; i < 4; ++i)
#pragma unroll
    for (int j = 0; j < 4; ++j) acc[i][j] = (f32x4){0.f, 0.f, 0.f, 0.f};
  float4 apf[4]; int4 bpf0, bpf1;
#pragma unroll
  for (int i = 0; i < 4; ++i) apf[i] = *(const float4*)(xp[i]);
  bpf0 = *(const int4*)(wp); bpf1 = *(const int4*)(wp + 4);
  for (int kt = 0; kt < NKT; ++kt) {
#pragma unroll
    for (int i = 0; i < 4; ++i) {
      H4 t;
      t.h2[0] = __floats2half2_rn(apf[i].x, apf[i].y);
      t.h2[1] = __floats2half2_rn(apf[i].z, apf[i].w);
      *reinterpret_cast<uint2*>(&As[arow[i] * LDT + ac4[i] * 4]) = t.u2;
    }
    {
      H8 r0, r1;
      r0.h2[0] = dequant_byte(bpf0.x, s2, b2); r0.h2[1] = dequant_byte(bpf0.y, s2, b2);
      r0.h2[2] = dequant_byte(bpf0.z, s2, b2); r0.h2[3] = dequant_byte(bpf0.w, s2, b2);
      r1.h2[0] = dequant_byte(bpf1.x, s2, b2); r1.h2[1] = dequant_byte(bpf1.y, s2, b2);
      r1.h2[2] = dequant_byte(bpf1.z, s2, b2); r1.h2[3] = dequant_byte(bpf1.w, s2, b2);
      *reinterpret_cast<uint4*>(&Bs[rowb * LDT + bhalf * 16 + 0]) = r0.u4;
      *reinterpret_cast<uint4*>(&Bs[rowb * LDT + bhalf * 16 + 8]) = r1.u4;
    }
    if (kt + 1 < NKT) {
#pragma unroll
      for (int i = 0; i < 4; ++i) apf[i] = *(const float4*)(xp[i] + (kt + 1) * BK);
      bpf0 = *(const int4*)(wp + (size_t)(kt + 1) * 16);
      bpf1 = *(const int4*)(wp + (size_t)(kt + 1) * 16 + 4);
    }
    __syncthreads();
    const int fm = lane & 15, q4 = lane >> 4;
    half8 af[4], bf[4];
#pragma unroll
    for (int i = 0; i < 4; ++i)
      af[i] = *reinterpret_cast<const half8*>(&As[(wm + i * 16 + fm) * LDT + q4 * 8]);
#pragma unroll
    for (int j = 0; j < 4; ++j)
      bf[j] = *reinterpret_cast<const half8*>(&Bs[(wn + j * 16 + fm) * LDT + q4 * 8]);
#pragma unroll
    for (int i = 0; i < 4; ++i)
#pragma unroll
      for (int j = 0; j < 4; ++j)
        acc[i][j] = __builtin_amdgcn_mfma_f32_16x16x32_f16(af[i], bf[j], acc[i][j], 0, 0, 0);
    __syncthreads();
  }
  const int col = lane & 15, r0q = (lane >> 4) * 4;
#pragma unroll
  for (int i = 0; i < 4; ++i)
#pragma unroll
    for (int j = 0; j < 4; ++j)
#pragma unroll
      for (int r = 0; r < 4; ++r)
        out[(size_t)(m0 + wm + i * 16 + r0q + r) * OUT_F + (n0 + wn + j * 16 + col)] = acc[i][j][r];
}

extern "C" void kernel_launch(void* const* d_in, const int* in_sizes, int n_in,
                              void* d_out, int out_size, void* d_ws, size_t ws_size,
                              hipStream_t stream) {
  const float* x     = (const float*)d_in[0];
  const int*   wq    = (const int*)d_in[1];     // integer inputs arrive as int32
  const float* scale = (const float*)d_in[2];
  const float* zero  = (const float*)d_in[3];
  float* out = (float*)d_out;

  const size_t xbytes = (size_t)TOKENS * IN_F * sizeof(__half);   // 33.5 MB
  const size_t wbytes = (size_t)OUT_F * IN_F * sizeof(__half);    // 90.2 MB

  if (ws_size >= xbytes + wbytes) {
    __half* xh = (__half*)d_ws;
    __half* wh = (__half*)((char*)d_ws + xbytes);
    convert_x_kernel<<<(TOKENS * IN_F) / 2048, 256, 0, stream>>>(x, xh);
    dequant_w_kernel<<<(OUT_F * (IN_F / 2)) / 2048, 256, 0, stream>>>(wq, scale, zero, wh);
    dim3 grid(OUT_F / BN, TOKENS / BM);
    gemm_f16_kernel<<<grid, 256, 0, stream>>>(xh, wh, out);
  } else {
    dim3 grid(OUT_F / BN, TOKENS / BM);
    int4_gemm_fused_kernel<<<grid, 256, 0, stream>>>(x, wq, scale, zero, out);
  }
}